// Round 1
// baseline (1596.971 us; speedup 1.0000x reference)
//
#include <hip/hip_runtime.h>
#include <math.h>

#define EPS 1e-6f
#define NE 64
#define THREADS 256
#define WAVES_PER_BLOCK (THREADS / 64)
#define NBLOCKS 1024
#define ITERS 10

__device__ __forceinline__ float wave_sum(float v) {
#pragma unroll
    for (int o = 32; o > 0; o >>= 1) v += __shfl_xor(v, o, 64);
    return v;
}

__device__ __forceinline__ float wave_max(float v) {
#pragma unroll
    for (int o = 32; o > 0; o >>= 1) v = fmaxf(v, __shfl_xor(v, o, 64));
    return v;
}

// ws layout: r[S] | c[64] | P[64]
__global__ void sink_init(float* __restrict__ r, float* __restrict__ c,
                          float* __restrict__ P, int S) {
    int i = blockIdx.x * blockDim.x + threadIdx.x;
    if (i < S) r[i] = 1.0f;
    if (i < NE) { c[i] = 1.0f; P[i] = 0.0f; }
}

// One fused Sinkhorn iteration pass: row-normalize (update r) and accumulate
// column partial sums P_j = sum_i q0_ij * r_i (with the updated r).
__global__ __launch_bounds__(THREADS) void sink_pass(
    const float* __restrict__ logits, float* __restrict__ r,
    const float* __restrict__ c, float* __restrict__ P, int S) {
    const int lane = threadIdx.x & 63;
    const int wib = threadIdx.x >> 6;
    const int gwave = blockIdx.x * WAVES_PER_BLOCK + wib;
    const int nwaves = gridDim.x * WAVES_PER_BLOCK;
    const float cj = c[lane];
    float pacc = 0.0f;

    for (int row = gwave; row < S; row += nwaves) {
        float v = logits[(size_t)row * NE + lane];
        float m = wave_max(v);
        float q = __expf(v - m);          // q0_ij
        float rold = r[row];              // broadcast load
        float s = wave_sum(q * cj);       // s_i = dot(q0_row, c)
        float rnew = rold / (rold * s + EPS);
        if (lane == 0) r[row] = rnew;
        pacc += q * rnew;
    }

    __shared__ float lds[WAVES_PER_BLOCK * 64];
    lds[wib * 64 + lane] = pacc;
    __syncthreads();
    if (wib == 0) {
        float t = 0.0f;
#pragma unroll
        for (int w = 0; w < WAVES_PER_BLOCK; ++w) t += lds[w * 64 + lane];
        atomicAdd(&P[lane], t);
    }
}

// c_j <- c_j * T / (c_j * P_j + eps); reset P for the next pass.
__global__ void sink_cupdate(float* __restrict__ c, float* __restrict__ P,
                             float col_target) {
    int j = threadIdx.x;
    if (j < NE) {
        float cj = c[j];
        float pj = P[j];
        c[j] = cj * col_target / (cj * pj + EPS);
        P[j] = 0.0f;
    }
}

// Final row-normalize + top-2 + weight renorm. Outputs:
// out_idx[2*S] (expert indices as float), out_w[2*S] (weights).
__global__ __launch_bounds__(THREADS) void sink_final(
    const float* __restrict__ logits, const float* __restrict__ r,
    const float* __restrict__ c, float* __restrict__ out_idx,
    float* __restrict__ out_w, int S) {
    const int lane = threadIdx.x & 63;
    const int wib = threadIdx.x >> 6;
    const int gwave = blockIdx.x * WAVES_PER_BLOCK + wib;
    const int nwaves = gridDim.x * WAVES_PER_BLOCK;
    const float cj = c[lane];

    for (int row = gwave; row < S; row += nwaves) {
        float v = logits[(size_t)row * NE + lane];
        float m = wave_max(v);
        float q = __expf(v - m);
        float u = q * cj;
        float rold = r[row];
        float s = wave_sum(u);
        float rnew = rold / (rold * s + EPS);
        float val = u * rnew;             // final q_ij

        // top-1 with JAX tie-break (lowest index wins on equal values)
        float v1 = val; int i1 = lane;
#pragma unroll
        for (int o = 32; o > 0; o >>= 1) {
            float ov = __shfl_xor(v1, o, 64);
            int oi = __shfl_xor(i1, o, 64);
            if (ov > v1 || (ov == v1 && oi < i1)) { v1 = ov; i1 = oi; }
        }
        // top-2: mask out the argmax lane, reduce again
        float masked = (lane == i1) ? -INFINITY : val;
        float v2 = masked; int i2 = lane;
#pragma unroll
        for (int o = 32; o > 0; o >>= 1) {
            float ov = __shfl_xor(v2, o, 64);
            int oi = __shfl_xor(i2, o, 64);
            if (ov > v2 || (ov == v2 && oi < i2)) { v2 = ov; i2 = oi; }
        }

        if (lane == 0) {
            float wsum = v1 + v2 + EPS;
            size_t o2 = (size_t)row * 2;
            out_idx[o2]     = (float)i1;
            out_idx[o2 + 1] = (float)i2;
            out_w[o2]     = v1 / wsum;
            out_w[o2 + 1] = v2 / wsum;
        }
    }
}

extern "C" void kernel_launch(void* const* d_in, const int* in_sizes, int n_in,
                              void* d_out, int out_size, void* d_ws, size_t ws_size,
                              hipStream_t stream) {
    const float* logits = (const float*)d_in[0];
    const int S = in_sizes[0] / NE;           // 524288
    const float col_target = (float)S / (float)NE;

    float* r = (float*)d_ws;                  // S floats
    float* c = r + S;                         // 64 floats
    float* P = c + NE;                        // 64 floats

    float* out = (float*)d_out;
    float* out_idx = out;                     // 2*S entries (indices as float)
    float* out_w = out + (size_t)2 * S;       // 2*S entries (weights)

    sink_init<<<(S + THREADS - 1) / THREADS, THREADS, 0, stream>>>(r, c, P, S);
    for (int it = 0; it < ITERS; ++it) {
        sink_pass<<<NBLOCKS, THREADS, 0, stream>>>(logits, r, c, P, S);
        sink_cupdate<<<1, 64, 0, stream>>>(c, P, col_target);
    }
    sink_final<<<NBLOCKS, THREADS, 0, stream>>>(logits, r, c, out_idx, out_w, S);
}

// Round 3
// 602.333 us; speedup vs baseline: 2.6513x; 2.6513x over previous
//
#include <hip/hip_runtime.h>
#include <math.h>

#define EPS 1e-6f
#define NE 64
#define THREADS 256
#define WPB 4            // waves per block
#define NBLOCKS 1024
#define ITERS 10

// ---- DPP helpers: 16-lane-group reductions, pure VALU (no ds_bpermute) ----
template <int ctrl>
__device__ __forceinline__ float dppf(float x) {
    return __int_as_float(__builtin_amdgcn_update_dpp(
        0, __float_as_int(x), ctrl, 0xf, 0xf, true));
}
template <int ctrl>
__device__ __forceinline__ int dppi(int x) {
    return __builtin_amdgcn_update_dpp(0, x, ctrl, 0xf, 0xf, true);
}

// sum across each 16-lane group (xor1, xor2, half_mirror, mirror)
__device__ __forceinline__ float group16_sum(float v) {
    v += dppf<0xB1>(v);   // quad_perm xor 1
    v += dppf<0x4E>(v);   // quad_perm xor 2
    v += dppf<0x141>(v);  // row_half_mirror
    v += dppf<0x140>(v);  // row_mirror
    return v;
}

#define ARGMAX_STEP(CTRL)                                      \
    {                                                          \
        float ov = dppf<CTRL>(v);                              \
        int oi = dppi<CTRL>(i);                                \
        if (ov > v || (ov == v && oi < i)) { v = ov; i = oi; } \
    }

// argmax (value, lowest index on ties) across each 16-lane group
__device__ __forceinline__ void group16_argmax(float& v, int& i) {
    ARGMAX_STEP(0xB1)
    ARGMAX_STEP(0x4E)
    ARGMAX_STEP(0x141)
    ARGMAX_STEP(0x140)
}

// ws layout: r[S] | c[64] | Pblk[NBLOCKS*64]
__global__ void sink_init(float* __restrict__ r, float* __restrict__ c, int S) {
    int i = blockIdx.x * blockDim.x + threadIdx.x;
    if (i < S) r[i] = 1.0f;
    if (i < NE) c[i] = 1.0f;
}

// One fused Sinkhorn iteration: 4 rows per wave, lane l handles row (l>>4),
// columns 4*(l&15)..+3. Row dot product via 16-lane DPP butterfly.
// Writes per-block column partials to Pblk[block][64] (NO atomics -> the
// downstream reduction is bitwise deterministic across graph replays).
__global__ __launch_bounds__(THREADS) void sink_pass(
    const float4* __restrict__ logits4, float* __restrict__ r,
    const float* __restrict__ c, float* __restrict__ Pblk, int nquads) {
    const int lane = threadIdx.x & 63;
    const int wib = threadIdx.x >> 6;
    const int g = lane >> 4;   // row within quad
    const int h = lane & 15;   // float4 slot within row

    const float4 c4 = ((const float4*)c)[h];

    float4 pacc = {0.f, 0.f, 0.f, 0.f};
    int wave = blockIdx.x * WPB + wib;
    int nw = gridDim.x * WPB;

    for (int quad = wave; quad < nquads; quad += nw) {
        float4 v = logits4[(size_t)quad * 64 + lane];
        float4 q;
        q.x = __expf(v.x); q.y = __expf(v.y);
        q.z = __expf(v.z); q.w = __expf(v.w);
        float s = q.x * c4.x + q.y * c4.y + q.z * c4.z + q.w * c4.w;
        s = group16_sum(s);
        int row = quad * 4 + g;
        float rold = r[row];
        float rnew = rold / (rold * s + EPS);
        if (h == 0) r[row] = rnew;
        pacc.x += q.x * rnew; pacc.y += q.y * rnew;
        pacc.z += q.z * rnew; pacc.w += q.w * rnew;
    }

    // block-level column reduction (fixed order), plain store of partials
    __shared__ float4 plds[WPB][64];
    plds[wib][lane] = pacc;
    __syncthreads();
    if (threadIdx.x < NE) {
        int j = threadIdx.x;
        int hh = j >> 2, kk = j & 3;
        float t = 0.f;
#pragma unroll
        for (int w = 0; w < WPB; ++w)
#pragma unroll
            for (int gg = 0; gg < 4; ++gg) {
                const float* p = (const float*)&plds[w][gg * 16 + hh];
                t += p[kk];
            }
        Pblk[blockIdx.x * NE + j] = t;
    }
}

// Deterministic column-sum over NBLOCKS partials (fixed order), then
// c_j <- c_j * T / (c_j * P_j + eps). One block, 1024 threads.
__global__ __launch_bounds__(1024) void sink_reduce(
    const float* __restrict__ Pblk, float* __restrict__ c, float col_target) {
    const int j = threadIdx.x & 63;      // column
    const int chunk = threadIdx.x >> 6;  // 16 chunks of NBLOCKS/16 blocks
    const int per = NBLOCKS / 16;
    float t = 0.f;
    int b0 = chunk * per;
    for (int b = b0; b < b0 + per; ++b) t += Pblk[b * NE + j];
    __shared__ float lds[16][NE];
    lds[chunk][j] = t;
    __syncthreads();
    if (threadIdx.x < NE) {
        float P = 0.f;
#pragma unroll
        for (int k = 0; k < 16; ++k) P += lds[k][threadIdx.x];
        float cj = c[threadIdx.x];
        c[threadIdx.x] = cj * col_target / (cj * P + EPS);
    }
}

// Final: row-normalize + top-2 (DPP argmax, lowest-index ties) + renorm.
__global__ __launch_bounds__(THREADS) void sink_final(
    const float4* __restrict__ logits4, const float* __restrict__ r,
    const float* __restrict__ c, float2* __restrict__ oidx,
    float2* __restrict__ ow, int nquads) {
    const int lane = threadIdx.x & 63;
    const int wib = threadIdx.x >> 6;
    const int g = lane >> 4;
    const int h = lane & 15;
    const int base_col = h * 4;

    const float4 c4 = ((const float4*)c)[h];

    int wave = blockIdx.x * WPB + wib;
    int nw = gridDim.x * WPB;

    for (int quad = wave; quad < nquads; quad += nw) {
        float4 vv = logits4[(size_t)quad * 64 + lane];
        float4 u;
        u.x = __expf(vv.x) * c4.x; u.y = __expf(vv.y) * c4.y;
        u.z = __expf(vv.z) * c4.z; u.w = __expf(vv.w) * c4.w;
        float s = group16_sum(u.x + u.y + u.z + u.w);
        int row = quad * 4 + g;
        float rold = r[row];
        float rnew = rold / (rold * s + EPS);
        float4 val;
        val.x = u.x * rnew; val.y = u.y * rnew;
        val.z = u.z * rnew; val.w = u.w * rnew;

        // top-1: per-lane best of 4 (lower col wins ties), then group argmax
        float v = val.x; int i = base_col;
        if (val.y > v) { v = val.y; i = base_col + 1; }
        if (val.z > v) { v = val.z; i = base_col + 2; }
        if (val.w > v) { v = val.w; i = base_col + 3; }
        group16_argmax(v, i);
        float v1 = v; int i1 = i;

        // top-2: mask out column i1, repeat
        float4 mv;
        mv.x = (i1 == base_col)     ? -INFINITY : val.x;
        mv.y = (i1 == base_col + 1) ? -INFINITY : val.y;
        mv.z = (i1 == base_col + 2) ? -INFINITY : val.z;
        mv.w = (i1 == base_col + 3) ? -INFINITY : val.w;
        v = mv.x; i = base_col;
        if (mv.y > v) { v = mv.y; i = base_col + 1; }
        if (mv.z > v) { v = mv.z; i = base_col + 2; }
        if (mv.w > v) { v = mv.w; i = base_col + 3; }
        group16_argmax(v, i);
        float v2 = v; int i2 = i;

        if (h == 0) {
            float wsum = v1 + v2 + EPS;
            oidx[row] = make_float2((float)i1, (float)i2);
            ow[row] = make_float2(v1 / wsum, v2 / wsum);
        }
    }
}

extern "C" void kernel_launch(void* const* d_in, const int* in_sizes, int n_in,
                              void* d_out, int out_size, void* d_ws, size_t ws_size,
                              hipStream_t stream) {
    const float* logits = (const float*)d_in[0];
    const int S = in_sizes[0] / NE;            // 524288
    const int nquads = S / 4;
    const float col_target = (float)S / (float)NE;

    float* r = (float*)d_ws;                   // S floats
    float* c = r + S;                          // 64 floats
    float* Pblk = c + NE;                      // NBLOCKS*64 floats

    float* out = (float*)d_out;
    float2* oidx = (float2*)out;               // 2*S floats (indices)
    float2* ow = (float2*)(out + (size_t)2 * S);  // 2*S floats (weights)

    sink_init<<<(S + THREADS - 1) / THREADS, THREADS, 0, stream>>>(r, c, S);
    for (int it = 0; it < ITERS; ++it) {
        sink_pass<<<NBLOCKS, THREADS, 0, stream>>>(
            (const float4*)logits, r, c, Pblk, nquads);
        sink_reduce<<<1, 1024, 0, stream>>>(Pblk, c, col_target);
    }
    sink_final<<<NBLOCKS, THREADS, 0, stream>>>(
        (const float4*)logits, r, c, oidx, ow, nquads);
}